// Round 4
// baseline (89.232 us; speedup 1.0000x reference)
//
#include <hip/hip_runtime.h>
#include <hip/hip_bf16.h>

// V[k,d] = sum_n a_bar[k,n]*x[d,n] - c[k,d]*sum_n a_bar[k,n]
// K=64, D=512, N=131072.
// Stage 1: LDS-staged split-N MFMA GEMM, 3-buffer 2-ahead pipeline with
//          counted vmcnt (T3+T4) -> bf16 partials (fragment layout) in d_ws.
// Stage 2: reduce partials + fused c*a_sum epilogue.

#define K_ROWS 64
#define D_COLS 512
#define N_RED  131072LL

#define DT     256               // d-cols per block (2 col-blocks cover D)
#define BK     32                // n-elements per K-step
#define XBYTES (DT * BK * 4)     // 32 KB x-tile
#define ABYTES (K_ROWS * BK * 4) // 8 KB a-tile
#define BUFB   (XBYTES + ABYTES) // 40 KB per buffer
#define NBUF   3                 // 120 KB LDS -> 1 block/CU

typedef __attribute__((ext_vector_type(8))) short short8;
typedef __attribute__((ext_vector_type(4))) float f32x4;

__device__ __forceinline__ short f2bf(float f) {
    __bf16 h = (__bf16)f;                  // RNE; pairs fuse to v_cvt_pk_bf16_f32
    return __builtin_bit_cast(short, h);
}

__device__ __forceinline__ float bf2f(unsigned short u) {
    return __builtin_bit_cast(float, (unsigned)u << 16);
}

__device__ __forceinline__ short8 cvt8(float4 a, float4 b) {
    short8 r;
    r[0] = f2bf(a.x); r[1] = f2bf(a.y); r[2] = f2bf(a.z); r[3] = f2bf(a.w);
    r[4] = f2bf(b.x); r[5] = f2bf(b.y); r[6] = f2bf(b.z); r[7] = f2bf(b.w);
    return r;
}

__device__ __forceinline__ void gload_lds16(const float* g, char* l) {
    __builtin_amdgcn_global_load_lds(
        (const __attribute__((address_space(1))) void*)g,
        (__attribute__((address_space(3))) void*)l, 16, 0, 0);
}

// Grid: 2*S blocks of 512 threads (8 waves), 1 block/CU (120 KB LDS).
// Block (g,s): d-cols [g*256,+256), n-chunk s. Wave w: d-cols [g*256+w*32,+32)
// x all 64 k-rows. XCD swizzle pairs (g=0,g=1) of the same s on one XCD so the
// a_bar window is L2-shared.
// LDS tiles XOR-swizzled via the per-lane GLOBAL source address (dest linear,
// required by global_load_lds); read offsets apply the same XOR.
// Per-wave staging = exactly 5 global_load_lds per K-step -> counted vmcnt:
//   prologue: stage(0), stage(1)
//   iter it:  vmcnt(5) [stage(it) done, stage(it+1) stays in flight]
//             s_barrier; stage(it+2); compute buf[it%3]
__global__ __launch_bounds__(512, 2) void vlad_stage1(
    const float* __restrict__ x, const float* __restrict__ ab,
    unsigned short* __restrict__ pax, float* __restrict__ pasum, int chunk)
{
    extern __shared__ char smem[];     // NBUF * BUFB = 120 KB
    const int nwg     = gridDim.x;     // 2*S, multiple of 8
    const int cpx     = nwg >> 3;
    const int logical = (blockIdx.x & 7) * cpx + (blockIdx.x >> 3);
    const int g   = logical & 1;
    const int s   = logical >> 1;
    const int tid = threadIdx.x;
    const int w   = tid >> 6;
    const int l   = tid & 63;
    const int lr  = l & 15;
    const int lg  = l >> 4;
    const int d0  = g * DT;
    const int wb  = tid & ~63;         // wave-uniform LDS unit base
    const size_t nblk = (size_t)s * chunk;
    const int steps   = chunk >> 5;
    const int swz     = lr & 7;

    // --- staging descriptors: 4 x-rounds + 1 a-round, 16B units ---
    const float* sg[5]; int sl[5];
    #pragma unroll
    for (int r2 = 0; r2 < 4; ++r2) {
        int u = r2 * 512 + tid, row = u >> 3, un = (u & 7) ^ (row & 7);
        sg[r2] = x + (size_t)(d0 + row) * N_RED + nblk + un * 4;
        sl[r2] = (r2 * 512 + wb) * 16;
    }
    {
        int row = tid >> 3, un = (tid & 7) ^ (row & 7);
        sg[4] = ab + (size_t)row * N_RED + nblk + un * 4;
        sl[4] = XBYTES + wb * 16;
    }
    auto stage = [&](int bi, int itn) {
        char* base = smem + bi * BUFB;
        #pragma unroll
        for (int j = 0; j < 5; ++j)
            gload_lds16(sg[j] + (size_t)itn * BK, base + sl[j]);
    };

    // --- fragment read offsets (bytes), swizzle matches staging ---
    int offx[2][2], offa[4][2];
    #pragma unroll
    for (int sub = 0; sub < 2; ++sub) {
        int xrow = w * 32 + sub * 16 + lr;
        #pragma unroll
        for (int cc = 0; cc < 2; ++cc)
            offx[sub][cc] = (xrow * 8 + ((lg * 2 + cc) ^ swz)) * 16;
    }
    #pragma unroll
    for (int t = 0; t < 4; ++t) {
        int arow = t * 16 + lr;
        #pragma unroll
        for (int cc = 0; cc < 2; ++cc)
            offa[t][cc] = XBYTES + (arow * 8 + ((lg * 2 + cc) ^ swz)) * 16;
    }

    f32x4 acc[4][2] = {};
    float asum[4] = {0.f, 0.f, 0.f, 0.f};
    const bool do_asum = (g == 0) && (w == 0);

    stage(0, 0);
    stage(1, 1);

    int cur = 0;
    #pragma unroll 1
    for (int it = 0; it < steps; ++it) {
        if (it + 1 < steps) asm volatile("s_waitcnt vmcnt(5)" ::: "memory");
        else                asm volatile("s_waitcnt vmcnt(0)" ::: "memory");
        __builtin_amdgcn_s_barrier();          // all waves staged buf[cur]
        asm volatile("" ::: "memory");         // fence: no LDS-read hoisting
        if (it + 2 < steps) {
            int nb = cur + 2; if (nb >= NBUF) nb -= NBUF;
            stage(nb, it + 2);                 // safe: everyone left buf[nb]
        }

        const char* b = smem + cur * BUFB;
        float4 a0[4], a1[4];
        #pragma unroll
        for (int t = 0; t < 4; ++t) {
            a0[t] = *(const float4*)(b + offa[t][0]);
            a1[t] = *(const float4*)(b + offa[t][1]);
        }
        float4 x0[2], x1[2];
        #pragma unroll
        for (int sub = 0; sub < 2; ++sub) {
            x0[sub] = *(const float4*)(b + offx[sub][0]);
            x1[sub] = *(const float4*)(b + offx[sub][1]);
        }
        if (do_asum) {
            #pragma unroll
            for (int t = 0; t < 4; ++t)
                asum[t] += ((a0[t].x + a0[t].y) + (a0[t].z + a0[t].w))
                         + ((a1[t].x + a1[t].y) + (a1[t].z + a1[t].w));
        }
        short8 xb0 = cvt8(x0[0], x1[0]);
        short8 xb1 = cvt8(x0[1], x1[1]);
        #pragma unroll
        for (int t = 0; t < 4; ++t) {
            short8 ab8 = cvt8(a0[t], a1[t]);
            acc[t][0] = __builtin_amdgcn_mfma_f32_16x16x32_bf16(ab8, xb0, acc[t][0], 0, 0, 0);
            acc[t][1] = __builtin_amdgcn_mfma_f32_16x16x32_bf16(ab8, xb1, acc[t][1], 0, 0, 0);
        }
        cur = (cur + 1 == NBUF) ? 0 : cur + 1;
    }

    // --- bf16 partials in fragment-layout order: fully-coalesced 128B lines.
    // f = ((((g*8+w)*4+t)*2+sub)*4+r)*64 + l ; k=t*16+lg*4+r, d=g*256+w*32+sub*16+lr
    unsigned short* dst = pax + (size_t)s * (K_ROWS * D_COLS);
    #pragma unroll
    for (int t = 0; t < 4; ++t)
        #pragma unroll
        for (int sub = 0; sub < 2; ++sub)
            #pragma unroll
            for (int r = 0; r < 4; ++r) {
                int fg = (((g * 8 + w) * 4 + t) * 2 + sub) * 4 + r;
                dst[fg * 64 + l] = (unsigned short)f2bf(acc[t][sub][r]);
            }

    if (do_asum) {
        #pragma unroll
        for (int t = 0; t < 4; ++t) {
            asum[t] += __shfl_xor(asum[t], 16, 64);
            asum[t] += __shfl_xor(asum[t], 32, 64);
        }
        if (l < 16)
            #pragma unroll
            for (int t = 0; t < 4; ++t)
                pasum[s * K_ROWS + t * 16 + l] = asum[t];
    }
}

// Grid: 32768/64 = 512 blocks of 256. Block covers 64 consecutive fragment
// indices (fixed g,w,t,sub,r; lg,lr vary): 4-way s-split + LDS combine,
// block-parallel a_sum reduce over the block's 4 k-rows.
__global__ __launch_bounds__(256) void vlad_stage2(
    const unsigned short* __restrict__ pax, const float* __restrict__ pasum,
    const float* __restrict__ c, float* __restrict__ out, int S)
{
    __shared__ float red[256];
    __shared__ float ared[256];
    const int t  = threadIdx.x;
    const int fo = t & 63;
    const int sp = t >> 6;
    const int fb = blockIdx.x * 64;
    const int f  = fb + fo;

    float acc = 0.f;
    for (int s = sp; s < S; s += 4)
        acc += bf2f(pax[(size_t)s * (K_ROWS * D_COLS) + f]);
    red[t] = acc;

    // a_sum for this block's 4 k-rows (lg = t&3)
    const int R = (fb >> 6) & 3, T = (fb >> 9) & 3;
    const int ka = T * 16 + (t & 3) * 4 + R;
    float pa = 0.f;
    for (int s2 = t >> 2; s2 < S; s2 += 64)
        pa += pasum[s2 * K_ROWS + ka];
    ared[t] = pa;
    __syncthreads();

    for (int st = 128; st >= 4; st >>= 1) {
        if (t < st) ared[t] += ared[t + st];
        __syncthreads();
    }
    if (sp == 0) {
        int lr = f & 15, lg = (f >> 4) & 3, r = (f >> 6) & 3;
        int sub = (f >> 8) & 1, tt = (f >> 9) & 3, w = (f >> 11) & 7, gg = (f >> 14) & 1;
        int k = tt * 16 + lg * 4 + r;
        int d = gg * 256 + w * 32 + sub * 16 + lr;
        float v = red[t] + red[t + 64] + red[t + 128] + red[t + 192];
        out[k * D_COLS + d] = v - c[k * D_COLS + d] * ared[lg];
    }
}

extern "C" void kernel_launch(void* const* d_in, const int* in_sizes, int n_in,
                              void* d_out, int out_size, void* d_ws, size_t ws_size,
                              hipStream_t stream)
{
    const float* x  = (const float*)d_in[0];
    const float* ab = (const float*)d_in[1];
    const float* c  = (const float*)d_in[2];
    float* out = (float*)d_out;

    // S=128 -> grid 256 (1 block/CU), pax 8 MB bf16; halve if ws too small.
    int S = 128;
    while (S > 4 &&
           (size_t)S * ((size_t)K_ROWS * D_COLS * 2 + K_ROWS * 4) > ws_size)
        S >>= 1;
    const int chunk = (int)(N_RED / S);

    unsigned short* pax = (unsigned short*)d_ws;
    float* pasum = (float*)((char*)d_ws + (size_t)S * K_ROWS * D_COLS * 2);

    vlad_stage1<<<dim3(2 * S), dim3(512), NBUF * BUFB, stream>>>(x, ab, pax, pasum, chunk);
    vlad_stage2<<<dim3((K_ROWS * D_COLS) / 64), dim3(256), 0, stream>>>(pax, pasum, c, out, S);
}

// Round 5
// 71.801 us; speedup vs baseline: 1.2428x; 1.2428x over previous
//
#include <hip/hip_runtime.h>
#include <hip/hip_bf16.h>

// V[k,d] = sum_n a_bar[k,n]*x[d,n] - c[k,d]*sum_n a_bar[k,n]
// K=64, D=512, N=131072.
// Stage 1: reg-staged bf16-LDS split-N MFMA GEMM, 12KB buffers x2, 3 blocks/CU,
//          T14 issue-early/write-late -> bf16 partials (fragment layout) in d_ws.
// Stage 2: reduce partials + fused c*a_sum epilogue.

#define K_ROWS 64
#define D_COLS 512
#define N_RED  131072LL
#define TOTAL_STEPS 4096          // N / 32
#define XBY 8192                  // bf16 x-tile: 128 rows x 32 n x 2B
#define ABY 4096                  // bf16 a-tile:  64 rows x 32 n x 2B
#define BUFB (XBY + ABY)          // 12 KB

typedef __attribute__((ext_vector_type(8))) short short8;
typedef __attribute__((ext_vector_type(4))) float f32x4;

static __device__ __forceinline__ short f2bf(float f) {
    __bf16 h = (__bf16)f;                  // RNE; pairs fuse to v_cvt_pk_bf16_f32
    return __builtin_bit_cast(short, h);
}
static __device__ __forceinline__ float bf2f(unsigned short u) {
    return __builtin_bit_cast(float, (unsigned)u << 16);
}
static __device__ __forceinline__ short8 cvt8(float4 a, float4 b) {
    short8 r;
    r[0] = f2bf(a.x); r[1] = f2bf(a.y); r[2] = f2bf(a.z); r[3] = f2bf(a.w);
    r[4] = f2bf(b.x); r[5] = f2bf(b.y); r[6] = f2bf(b.z); r[7] = f2bf(b.w);
    return r;
}

// Grid: 4*S blocks of 512 threads (8 waves), 24KB LDS, 3 blocks/CU.
// bid = m*32 + g*8 + x7:  col-group g in 0..3 (d-cols [g*128,+128)),
// n-chunk s = m*8 + x7 — the 4 g's of one s share x7 => same XCD (a_bar
// window L2-shared). Uneven K-step split: block s covers steps
// [s*4096/S, (s+1)*4096/S).
// LDS tiles bf16, row = 64B = 4 x 16B units, unit slot ^= (row>>1)&3
// (2-way banks max on both ds_write_b128 and frag ds_read_b128).
// Per K-step: barrier -> issue next loads (T14) -> 5 ds_read + 4 MFMA ->
// cvt + ds_write next buffer.
__global__ __launch_bounds__(512, 6) void vlad_stage1(
    const float* __restrict__ x, const float* __restrict__ ab,
    unsigned short* __restrict__ pax, float* __restrict__ pasum, int S)
{
    __shared__ __align__(16) char smem[2][BUFB];

    const int bid = blockIdx.x;
    const int x7  = bid & 7;
    const int g   = (bid >> 3) & 3;
    const int m   = bid >> 5;
    const int s   = m * 8 + x7;
    const int tid = threadIdx.x;
    const int w   = tid >> 6, l = tid & 63, lr = l & 15, lg = l >> 4;
    const int d0  = g * 128;

    const int st0 = (int)(((long long)s       * TOTAL_STEPS) / S);
    const int st1 = (int)(((long long)(s + 1) * TOTAL_STEPS) / S);

    // ---- staging geometry: thread owns one 16B bf16 unit of x (and a if tid<256)
    const int xrow = tid >> 2, xslot = tid & 3;
    const int xoff = xrow * 64 + ((xslot ^ ((xrow >> 1) & 3)) << 4);
    const float* gx = x + (size_t)(d0 + xrow) * N_RED + xslot * 8;

    const int aoff = ABY ? (XBY + xrow * 64 + ((xslot ^ ((xrow >> 1) & 3)) << 4)) : 0;
    const float* ga = ab + (size_t)xrow * N_RED + xslot * 8;   // valid tid<256
    const bool at = (tid < 256);

    // ---- fragment read offsets (swizzle matches staging; row>>1&3 == lr>>1&3
    //      because 16-row fragment blocks are 16-aligned)
    const int swz = (lr >> 1) & 3;
    const int fxo = (w * 16 + lr) * 64 + ((lg ^ swz) << 4);
    int fao[4];
    #pragma unroll
    for (int t = 0; t < 4; ++t)
        fao[t] = XBY + (t * 16 + lr) * 64 + ((lg ^ swz) << 4);

    f32x4 acc[4] = {};
    float asum = 0.f;
    float4 L0, L1, L2, L3;

    auto issue = [&](int it) {
        const float* p = gx + (size_t)it * 32;
        L0 = *(const float4*)(p);
        L1 = *(const float4*)(p + 4);
        if (at) {
            const float* q = ga + (size_t)it * 32;
            L2 = *(const float4*)(q);
            L3 = *(const float4*)(q + 4);
        }
    };
    auto commit = [&](char* buf) {
        *(short8*)(buf + xoff) = cvt8(L0, L1);
        if (at) {
            *(short8*)(buf + aoff) = cvt8(L2, L3);
            float ssum = ((L2.x + L2.y) + (L2.z + L2.w))
                       + ((L3.x + L3.y) + (L3.z + L3.w));
            ssum += __shfl_xor(ssum, 1, 64);     // reduce the 4 slots of a row
            ssum += __shfl_xor(ssum, 2, 64);
            asum += ssum;
        }
    };

    issue(st0);
    commit(smem[0]);

    int cur = 0;
    #pragma unroll 1
    for (int it = st0; it < st1; ++it) {
        const bool more = (it + 1 < st1);
        __syncthreads();              // buf[cur] writes drained; buf[cur^1] free
        if (more) issue(it + 1);      // loads fly under the MFMA phase (T14)

        const char* b = smem[cur];
        short8 xf  = *(const short8*)(b + fxo);
        short8 a0f = *(const short8*)(b + fao[0]);
        short8 a1f = *(const short8*)(b + fao[1]);
        short8 a2f = *(const short8*)(b + fao[2]);
        short8 a3f = *(const short8*)(b + fao[3]);
        acc[0] = __builtin_amdgcn_mfma_f32_16x16x32_bf16(a0f, xf, acc[0], 0, 0, 0);
        acc[1] = __builtin_amdgcn_mfma_f32_16x16x32_bf16(a1f, xf, acc[1], 0, 0, 0);
        acc[2] = __builtin_amdgcn_mfma_f32_16x16x32_bf16(a2f, xf, acc[2], 0, 0, 0);
        acc[3] = __builtin_amdgcn_mfma_f32_16x16x32_bf16(a3f, xf, acc[3], 0, 0, 0);

        if (more) commit(smem[cur ^ 1]);   // cvt waits vmcnt; write-late
        cur ^= 1;
    }

    // bf16 partials, fragment-layout: f = (((g*8+w)*4+t)*4+r)*64 + l
    // (k = t*16+lg*4+r, d = g*128+w*16+lr) — coalesced 128B lines.
    unsigned short* dst = pax + (size_t)s * (K_ROWS * D_COLS);
    #pragma unroll
    for (int t = 0; t < 4; ++t)
        #pragma unroll
        for (int r = 0; r < 4; ++r)
            dst[(((g * 8 + w) * 4 + t) * 4 + r) * 64 + l] =
                (unsigned short)f2bf(acc[t][r]);

    // a_sum: tid<256 staged a-row (tid>>2); quad already reduced each step.
    if (g == 0 && at && (tid & 3) == 0)
        pasum[s * K_ROWS + (tid >> 2)] = asum;
}

// Grid: 32768/64 = 512 blocks of 256. Block covers 64 consecutive fragment
// indices (fixed g,w,t,r; lg,lr vary): 4-way s-split + LDS combine,
// block-parallel a_sum reduce over the block's 4 k-rows.
__global__ __launch_bounds__(256) void vlad_stage2(
    const unsigned short* __restrict__ pax, const float* __restrict__ pasum,
    const float* __restrict__ c, float* __restrict__ out, int S)
{
    __shared__ float red[256];
    __shared__ float ared[256];
    const int t  = threadIdx.x;
    const int fo = t & 63;
    const int sp = t >> 6;
    const int fb = blockIdx.x * 64;
    const int f  = fb + fo;

    float acc = 0.f;
    for (int s = sp; s < S; s += 4)
        acc += bf2f(pax[(size_t)s * (K_ROWS * D_COLS) + f]);
    red[t] = acc;

    // a_sum partials for this block's 4 k-rows (indexed by lg = t&3)
    const int R = (fb >> 6) & 3, T = (fb >> 8) & 3;
    const int ka = T * 16 + (t & 3) * 4 + R;
    float pa = 0.f;
    for (int s2 = t >> 2; s2 < S; s2 += 64)
        pa += pasum[s2 * K_ROWS + ka];
    ared[t] = pa;
    __syncthreads();

    for (int st = 128; st >= 4; st >>= 1) {
        if (t < st) ared[t] += ared[t + st];
        __syncthreads();
    }
    if (sp == 0) {
        const int lr = f & 15, lg = (f >> 4) & 3;
        const int r  = (f >> 6) & 3, tt = (f >> 8) & 3;
        const int w  = (f >> 10) & 7, gg = (f >> 13) & 3;
        const int k  = tt * 16 + lg * 4 + r;
        const int d  = gg * 128 + w * 16 + lr;
        float v = red[t] + red[t + 64] + red[t + 128] + red[t + 192];
        out[k * D_COLS + d] = v - c[k * D_COLS + d] * ared[lg];
    }
}

extern "C" void kernel_launch(void* const* d_in, const int* in_sizes, int n_in,
                              void* d_out, int out_size, void* d_ws, size_t ws_size,
                              hipStream_t stream)
{
    const float* x  = (const float*)d_in[0];
    const float* ab = (const float*)d_in[1];
    const float* c  = (const float*)d_in[2];
    float* out = (float*)d_out;

    // S=192 -> grid 768 = exactly 3 blocks/CU; halve if ws too small
    // (S must stay a multiple of 8 for the XCD mapping).
    int S = 192;
    while (S > 24 &&
           (size_t)S * ((size_t)K_ROWS * D_COLS * 2 + K_ROWS * 4) > ws_size)
        S >>= 1;

    unsigned short* pax = (unsigned short*)d_ws;
    float* pasum = (float*)((char*)d_ws + (size_t)S * K_ROWS * D_COLS * 2);

    vlad_stage1<<<dim3(4 * S), dim3(512), 0, stream>>>(x, ab, pax, pasum, S);
    vlad_stage2<<<dim3((K_ROWS * D_COLS) / 64), dim3(256), 0, stream>>>(pax, pasum, c, out, S);
}